// Round 6
// baseline (541.480 us; speedup 1.0000x reference)
//
#include <hip/hip_runtime.h>
#include <hip/hip_bf16.h>

typedef unsigned short u16;
typedef __attribute__((ext_vector_type(8))) short short8;
typedef __attribute__((ext_vector_type(4))) float f32x4;

#define NE 131072

// ws layout in u16 elements (bf16 transposed weights, [n][k] row-major)
#define OFF_WA 0        // 4 x [256][256]
#define OFF_WB 262144   // 4 x [128][256]
#define OFF_WF 393216   // 4 x [128][128]
#define OFF_WE 458752   // [128][32]
#define OFF_WS 462848   // [128]

// async global->LDS, 16B per lane, lane i lands at lds_base + 16*i
#define ASYNC16(gp, lp) __builtin_amdgcn_global_load_lds( \
    (const __attribute__((address_space(1))) unsigned int*)(gp), \
    (__attribute__((address_space(3))) unsigned int*)(lp), 16, 0, 0)
// wait lgkmcnt(0) only: ds_read data in VGPRs before we re-DMA that LDS slot.
#define LGKM0() __builtin_amdgcn_s_waitcnt(0xC07F)
// counted waits for the 3-deep chunk pipeline (2 loads per chunk).
#define WAIT4() asm volatile("s_waitcnt vmcnt(4)" ::: "memory")
#define WAIT2() asm volatile("s_waitcnt vmcnt(2)" ::: "memory")
#define WAIT0() asm volatile("s_waitcnt vmcnt(0)" ::: "memory")
// non-draining barrier: cross-wave data moves only through LDS (ds ops), so
// lgkmcnt(0) + s_barrier is sufficient; the weight DMA (vmcnt) is wave-private
// and intentionally stays in flight across the barrier (T4: never drain).
#define BAR() asm volatile("s_waitcnt lgkmcnt(0)\n\ts_barrier" ::: "memory")

__device__ __forceinline__ float b2f(u16 v) {
    unsigned int u = ((unsigned int)v) << 16;
    float f;
    __builtin_memcpy(&f, &u, 4);
    return f;
}
__device__ __forceinline__ u16 f2b(float f) {
    __hip_bfloat16 h = __float2bfloat16(f);
    u16 u;
    __builtin_memcpy(&u, &h, 2);
    return u;
}
__device__ __forceinline__ short8 pack8(f32x4 a, f32x4 b) {
    short8 p;
    p[0] = (short)f2b(a.x); p[1] = (short)f2b(a.y);
    p[2] = (short)f2b(a.z); p[3] = (short)f2b(a.w);
    p[4] = (short)f2b(b.x); p[5] = (short)f2b(b.y);
    p[6] = (short)f2b(b.z); p[7] = (short)f2b(b.w);
    return p;
}

#define MFMA16(a, b, c) __builtin_amdgcn_mfma_f32_16x16x32_bf16(a, b, c, 0, 0, 0)

struct BiasP {
    const float* ba[4];
    const float* bb[4];
};

// ---- uniform 2-KB weight chunks, wave-private 3-slot rotation ----
// Chunk = [32 weight rows][32 k] bf16 = 2 KB = 2 global_load_lds. Per block:
// per m-group 28 chunks (A: 16 = 8 kk x 2 col-halves, B: 8, C: 4) -> 112.
// Chunk gc lives in slot (gc % 3) of the wave's 6-KB third. k-slot is
// XOR-swizzled by the same function on DMA source and LDS read.
__device__ __forceinline__ void issue_chunk(const u16* __restrict__ ws, u16* Wb,
                                            int wave, int lane, int gc) {
    if (gc >= 112) return;
    const int m = gc / 28;
    const int c = gc - m * 28;
    const int r = lane >> 2;                        // row 0..15 within 16-row group
    const int slot = (lane & 3) ^ ((lane >> 3) & 3); // pre-swizzled k-slot
    u16* lp = Wb + wave * 3072 + (gc % 3) * 1024;
    const u16* gp;
    int rstride;
    if (c < 16) {            // stage A: Wa_m [256][256], wave cols = wave*64 + (c&1)*32
        int kk = c >> 1, nh = c & 1;
        gp = ws + OFF_WA + m * 65536
           + (size_t)(wave * 64 + nh * 32 + r) * 256 + kk * 32 + slot * 8;
        rstride = 16 * 256;
    } else if (c < 24) {     // stage B: Wb_m [128][256], wave cols = wave*32
        int kc = c - 16;
        gp = ws + OFF_WB + m * 32768
           + (size_t)(wave * 32 + r) * 256 + kc * 32 + slot * 8;
        rstride = 16 * 256;
    } else {                 // stage C: Wf_m [128][128]
        int cc = c - 24;
        gp = ws + OFF_WF + m * 16384
           + (size_t)(wave * 32 + r) * 128 + cc * 32 + slot * 8;
        rstride = 16 * 128;
    }
    ASYNC16(gp, lp);
    ASYNC16(gp + rstride, lp + 512);
}

// LDS-tiled transpose prep: coalesced reads AND writes.
__global__ __launch_bounds__(256)
void prep_kernel(const float* __restrict__ W1a, const float* __restrict__ W2a,
                 const float* __restrict__ W3a, const float* __restrict__ W4a,
                 const float* __restrict__ W1b, const float* __restrict__ W2b,
                 const float* __restrict__ W3b, const float* __restrict__ W4b,
                 const float* __restrict__ Wf,  u16* __restrict__ ws) {
    __shared__ __align__(16) u16 T[64 * 80];

    const int y = blockIdx.y;
    const int t = threadIdx.x;
    const float* in;
    int K, N;
    if (y < 4)      { in = (y == 0) ? W1a : (y == 1) ? W2a : (y == 2) ? W3a : W4a; K = 256; N = 256; }
    else if (y < 8) { in = (y == 4) ? W1b : (y == 5) ? W2b : (y == 6) ? W3b : W4b; K = 256; N = 128; }
    else            { in = Wf; K = 545; N = 128; }

    const int ntilesN = N / 64;
    const int ktiles = (K + 63) / 64;
    const int kt = blockIdx.x / ntilesN;
    const int nt = blockIdx.x - kt * ntilesN;
    if (kt >= ktiles) return;
    const int kbase = kt * 64, nbase = nt * 64;

    {
        int tn = (t & 15) * 4;
        int tk = t >> 4;
        #pragma unroll
        for (int r = 0; r < 4; r++) {
            int k = kbase + tk + 16 * r;
            if (k < K) {
                float4 v = *(const float4*)(in + (size_t)k * N + nbase + tn);
                T[(tn + 0) * 80 + tk + 16 * r] = f2b(v.x);
                T[(tn + 1) * 80 + tk + 16 * r] = f2b(v.y);
                T[(tn + 2) * 80 + tk + 16 * r] = f2b(v.z);
                T[(tn + 3) * 80 + tk + 16 * r] = f2b(v.w);
            }
        }
    }
    __syncthreads();
    {
        int n = t >> 2;
        int kc = (t & 3) * 16;
        int n_out = nbase + n;
        const u16* src = &T[n * 80 + kc];
        if (y < 4) {
            u16* dst = ws + OFF_WA + y * 65536 + (size_t)n_out * 256 + kbase + kc;
            *(short8*)dst = *(const short8*)src;
            *(short8*)(dst + 8) = *(const short8*)(src + 8);
        } else if (y < 8) {
            u16* dst = ws + OFF_WB + (y - 4) * 32768 + (size_t)n_out * 256 + kbase + kc;
            *(short8*)dst = *(const short8*)src;
            *(short8*)(dst + 8) = *(const short8*)(src + 8);
        } else if (kbase < 512) {
            u16* dst = ws + OFF_WF + (kbase >> 7) * 16384 + (size_t)n_out * 128 + (kbase & 127) + kc;
            *(short8*)dst = *(const short8*)src;
            *(short8*)(dst + 8) = *(const short8*)(src + 8);
        } else {
            #pragma unroll
            for (int j = 0; j < 16; j++) {
                int k = kbase + kc + j;
                if (k < 545) {
                    u16 v = src[j];
                    if (k == 512)      ws[OFF_WS + n_out] = v;
                    else               ws[OFF_WE + n_out * 32 + (k - 513)] = v;
                }
            }
        }
    }
}

// 64 edges/block, 4 waves, ~126 KB LDS -> 1 block/CU (4 waves).
// Same depth-3 counted-vmcnt weight pipeline + non-draining barriers as r5,
// but each chunk now feeds 2x the MFMA work (64 edge rows), doubling the
// pipeline's latency-hiding budget and halving per-edge weight traffic.
// G overlays Hs cols 0..127. Barrier/hazard order per m:
//   A reads Xs/Xd, writes Hs | BAR_A | B reads Hs | BAR_B2 |
//   G-write (Hs cols<128)    | BAR_B | C reads G  | BAR_C (m<3) |
// Epilogue os overlays Xs (last Xs read is A(3), fenced by BAR_A(3)).
__global__ __launch_bounds__(256, 1)
void fused_kernel(const float* __restrict__ x, const int* __restrict__ ei,
                  const float* __restrict__ ea, const u16* __restrict__ ws,
                  BiasP bp, const float* __restrict__ bfp, float* __restrict__ out) {
    __shared__ __align__(16) u16 Xs[64][264];
    __shared__ __align__(16) u16 Xd[64][264];
    __shared__ __align__(16) u16 Hs[64][264];   // cols 0..127 double as G
    __shared__ __align__(16) u16 Wb[12288];     // 24 KB, 6-KB third per wave (3 slots)
    __shared__ float scos[64];

    const int t = threadIdx.x;
    const int wave = t >> 6;
    const int lane = t & 63;
    const int l15 = lane & 15;
    const int g = lane >> 4;
    const int e0 = blockIdx.x * 64;
    const f32x4 zero4 = {0.f, 0.f, 0.f, 0.f};
    const int colA = wave * 64;
    const int colC = wave * 32;

    // Hedge: detect int64 edge_index (sampled high words all zero) vs int32.
    bool idx64 = true;
    #pragma unroll
    for (int i = 1; i < 16; i += 2) { idx64 = idx64 && (ei[i] == 0); }

    // ---- bias hoist (issued before chunk priming -> older vmcnt entries) ----
    float biasA[4][4], biasB[4][2];
    #pragma unroll
    for (int m = 0; m < 4; m++) {
        #pragma unroll
        for (int nt = 0; nt < 4; nt++) biasA[m][nt] = bp.ba[m][colA + nt * 16 + l15];
        #pragma unroll
        for (int nt = 0; nt < 2; nt++) biasB[m][nt] = bp.bb[m][colC + nt * 16 + l15];
    }

    // prime the 3-deep pipeline; chunks land during the gather
    issue_chunk(ws, Wb, wave, lane, 0);
    issue_chunk(ws, Wb, wave, lane, 1);
    issue_chunk(ws, Wb, wave, lane, 2);

    // ---- gather (f32 -> bf16 tiles) + cosine similarity in one pass ----
    // 4 lanes per edge, 64 floats per lane per row.
    {
        int edge = t >> 2;
        int c = t & 3;
        int pos = e0 + edge;
        int is = idx64 ? ei[2 * pos] : ei[pos];
        int id = idx64 ? ei[2 * (NE + pos)] : ei[NE + pos];
        const float* rs = x + (size_t)is * 256 + c * 64;
        const float* rd = x + (size_t)id * 256 + c * 64;
        float dot = 0.f, ss = 0.f, dd = 0.f;
        #pragma unroll
        for (int i = 0; i < 8; i++) {
            f32x4 s0 = *(const f32x4*)(rs + i * 8);
            f32x4 s1 = *(const f32x4*)(rs + i * 8 + 4);
            f32x4 d0 = *(const f32x4*)(rd + i * 8);
            f32x4 d1 = *(const f32x4*)(rd + i * 8 + 4);
            dot += s0.x * d0.x + s0.y * d0.y + s0.z * d0.z + s0.w * d0.w
                 + s1.x * d1.x + s1.y * d1.y + s1.z * d1.z + s1.w * d1.w;
            ss  += s0.x * s0.x + s0.y * s0.y + s0.z * s0.z + s0.w * s0.w
                 + s1.x * s1.x + s1.y * s1.y + s1.z * s1.z + s1.w * s1.w;
            dd  += d0.x * d0.x + d0.y * d0.y + d0.z * d0.z + d0.w * d0.w
                 + d1.x * d1.x + d1.y * d1.y + d1.z * d1.z + d1.w * d1.w;
            *(short8*)(&Xs[edge][c * 64 + i * 8]) = pack8(s0, s1);
            *(short8*)(&Xd[edge][c * 64 + i * 8]) = pack8(d0, d1);
        }
        dot += __shfl_xor(dot, 1); ss += __shfl_xor(ss, 1); dd += __shfl_xor(dd, 1);
        dot += __shfl_xor(dot, 2); ss += __shfl_xor(ss, 2); dd += __shfl_xor(dd, 2);
        if (c == 0) {
            float ns = fmaxf(sqrtf(ss), 1e-8f);
            float nd = fmaxf(sqrtf(dd), 1e-8f);
            scos[edge] = dot / (ns * nd);
        }
    }
    BAR();             // gather barrier: Xs/Xd/scos visible; DMA stays in flight

    // ---- LDS read base pointers (per mt row-group) ----
    const u16* xsb[4]; const u16* xdb[4]; const u16* hgb[4];
    #pragma unroll
    for (int mt = 0; mt < 4; mt++) {
        xsb[mt] = &Xs[mt * 16 + l15][g * 8];
        xdb[mt] = &Xd[mt * 16 + l15][g * 8];
        hgb[mt] = &Hs[mt * 16 + l15][g * 8];
    }
    // weight frag base: row = nt*16 + l15, k-slot g XOR-swizzled by (l15>>1)&3
    const u16* wbase = Wb + wave * 3072 + l15 * 32 + ((g ^ ((l15 >> 1) & 3)) * 8);

    f32x4 Facc[4][2];
    #pragma unroll
    for (int a = 0; a < 4; a++) {
        #pragma unroll
        for (int b = 0; b < 2; b++) Facc[a][b] = zero4;
    }

    #pragma unroll
    for (int m = 0; m < 4; m++) {
        // ===== stage A: H = relu(A @ Wa + ba) ===== (16 chunks: 8 kk x 2 col-halves)
        f32x4 accA[4][4];
        #pragma unroll
        for (int a = 0; a < 4; a++) {
            #pragma unroll
            for (int b = 0; b < 4; b++) accA[a][b] = zero4;
        }
        #pragma unroll
        for (int kk = 0; kk < 8; kk++) {
            const int gc = m * 28 + kk * 2;
            // af frags first (stable LDS + VALU repack overlap the DMA wait)
            short8 af[4];
            #pragma unroll
            for (int mt = 0; mt < 4; mt++) {
                if (m == 0)      af[mt] = *(const short8*)(xsb[mt] + kk * 32);
                else if (m == 1) af[mt] = *(const short8*)(xdb[mt] + kk * 32);
                else {
                    short8 s = *(const short8*)(xsb[mt] + kk * 32);
                    short8 d = *(const short8*)(xdb[mt] + kk * 32);
                    short8 rr;
                    #pragma unroll
                    for (int j = 0; j < 8; j++) {
                        float fs = b2f((u16)s[j]);
                        float fd = b2f((u16)d[j]);
                        rr[j] = (short)f2b((m == 2) ? (fs - fd) : (fs * fd));
                    }
                    af[mt] = rr;
                }
            }
            // ---- chunk gc (col-half 0) ----
            WAIT4();
            const u16* wq0 = wbase + (gc % 3) * 1024;
            short8 wf0 = *(const short8*)(wq0);
            short8 wf1 = *(const short8*)(wq0 + 512);
            LGKM0();
            issue_chunk(ws, Wb, wave, lane, gc + 3);
            #pragma unroll
            for (int mt = 0; mt < 4; mt++) {
                accA[mt][0] = MFMA16(af[mt], wf0, accA[mt][0]);
                accA[mt][1] = MFMA16(af[mt], wf1, accA[mt][1]);
            }
            // ---- chunk gc+1 (col-half 1) ----
            WAIT4();
            const u16* wq1 = wbase + ((gc + 1) % 3) * 1024;
            short8 wf2 = *(const short8*)(wq1);
            short8 wf3 = *(const short8*)(wq1 + 512);
            LGKM0();
            issue_chunk(ws, Wb, wave, lane, gc + 4);
            #pragma unroll
            for (int mt = 0; mt < 4; mt++) {
                accA[mt][2] = MFMA16(af[mt], wf2, accA[mt][2]);
                accA[mt][3] = MFMA16(af[mt], wf3, accA[mt][3]);
            }
        }
        #pragma unroll
        for (int nt = 0; nt < 4; nt++) {
            int col = colA + nt * 16 + l15;
            #pragma unroll
            for (int mt = 0; mt < 4; mt++) {
                #pragma unroll
                for (int rg = 0; rg < 4; rg++) {
                    int row = mt * 16 + g * 4 + rg;
                    Hs[row][col] = f2b(fmaxf(accA[mt][nt][rg] + biasA[m][nt], 0.f));
                }
            }
        }
        BAR();                                   // BAR_A: Hs ready (DMA in flight)

        // ===== stage B: G = relu(H @ Wb + bb) ===== (8 chunks of 32-k)
        f32x4 accB[4][2];
        #pragma unroll
        for (int a = 0; a < 4; a++) {
            #pragma unroll
            for (int b = 0; b < 2; b++) accB[a][b] = zero4;
        }
        #pragma unroll
        for (int kc = 0; kc < 8; kc++) {
            const int gc = m * 28 + 16 + kc;
            short8 hf[4];
            #pragma unroll
            for (int mt = 0; mt < 4; mt++) hf[mt] = *(const short8*)(hgb[mt] + kc * 32);
            WAIT4();
            const u16* wq = wbase + (gc % 3) * 1024;
            short8 wf0 = *(const short8*)(wq);
            short8 wf1 = *(const short8*)(wq + 512);
            LGKM0();
            issue_chunk(ws, Wb, wave, lane, gc + 3);
            #pragma unroll
            for (int mt = 0; mt < 4; mt++) {
                accB[mt][0] = MFMA16(hf[mt], wf0, accB[mt][0]);
                accB[mt][1] = MFMA16(hf[mt], wf1, accB[mt][1]);
            }
        }
        BAR();                                   // BAR_B2: all H reads done
        #pragma unroll
        for (int nt = 0; nt < 2; nt++) {
            int col = colC + nt * 16 + l15;      // cols 0..127: G overlays Hs
            #pragma unroll
            for (int mt = 0; mt < 4; mt++) {
                #pragma unroll
                for (int rg = 0; rg < 4; rg++) {
                    int row = mt * 16 + g * 4 + rg;
                    Hs[row][col] = f2b(fmaxf(accB[mt][nt][rg] + biasB[m][nt], 0.f));
                }
            }
        }
        BAR();                                   // BAR_B: G ready

        // ===== stage C: Facc += G @ WfT_m ===== (4 chunks of 32-k)
        #pragma unroll
        for (int cc = 0; cc < 4; cc++) {
            const int gc = m * 28 + 24 + cc;
            short8 gf[4];
            #pragma unroll
            for (int mt = 0; mt < 4; mt++) gf[mt] = *(const short8*)(hgb[mt] + cc * 32);
            // tail ramp-down: at gc=110 only {110,111} outstanding; at 111 only {111}
            if (m == 3 && cc == 2)      { WAIT2(); }
            else if (m == 3 && cc == 3) { WAIT0(); }
            else                        { WAIT4(); }
            const u16* wq = wbase + (gc % 3) * 1024;
            short8 wf0 = *(const short8*)(wq);
            short8 wf1 = *(const short8*)(wq + 512);
            LGKM0();
            issue_chunk(ws, Wb, wave, lane, gc + 3);
            #pragma unroll
            for (int mt = 0; mt < 4; mt++) {
                Facc[mt][0] = MFMA16(gf[mt], wf0, Facc[mt][0]);
                Facc[mt][1] = MFMA16(gf[mt], wf1, Facc[mt][1]);
            }
        }
        if (m < 3) BAR();                        // BAR_C: G reads done before Hs(m+1) writes
    }

    // ===== edge_attr contribution (loaded after m-loop: dead across it) =====
    short8 eaA[4], eaB[2];
    float epi_b[2], epi_w[2];
    #pragma unroll
    for (int mt = 0; mt < 4; mt++) {
        const float* er = ea + (size_t)(e0 + mt * 16 + l15) * 32 + g * 8;
        f32x4 a = *(const f32x4*)(er);
        f32x4 b = *(const f32x4*)(er + 4);
        eaA[mt] = pack8(a, b);
    }
    #pragma unroll
    for (int nt = 0; nt < 2; nt++) {
        int col = colC + nt * 16 + l15;
        eaB[nt] = *(const short8*)(ws + OFF_WE + col * 32 + g * 8);
        epi_b[nt] = bfp[col];
        epi_w[nt] = b2f(ws[OFF_WS + col]);
    }
    #pragma unroll
    for (int mt = 0; mt < 4; mt++) {
        #pragma unroll
        for (int nt = 0; nt < 2; nt++) {
            Facc[mt][nt] = MFMA16(eaA[mt], eaB[nt], Facc[mt][nt]);
        }
    }

    // ===== epilogue: + s*Wf[512] + bf, tanh, stage f32 in LDS, coalesced store =====
    float* os = (float*)&Xs[0][0];   // reuse Xs: 64 x 132 f32 = 33792 B (exact fit)
    #pragma unroll
    for (int nt = 0; nt < 2; nt++) {
        int col = colC + nt * 16 + l15;
        #pragma unroll
        for (int mt = 0; mt < 4; mt++) {
            #pragma unroll
            for (int rg = 0; rg < 4; rg++) {
                int row = mt * 16 + g * 4 + rg;
                float v = Facc[mt][nt][rg] + scos[row] * epi_w[nt] + epi_b[nt];
                v = fminf(fmaxf(v, -15.f), 15.f);
                float e2 = __expf(2.f * v);
                os[row * 132 + col] = (e2 - 1.f) / (e2 + 1.f);
            }
        }
    }
    BAR();
    {
        int row = t >> 2, c = t & 3;
        float* op = out + (size_t)(e0 + row) * 128 + c * 32;
        const float* sp = os + row * 132 + c * 32;
        #pragma unroll
        for (int i = 0; i < 8; i++) {
            f32x4 v = *(const f32x4*)(sp + i * 4);
            *(f32x4*)(op + i * 4) = v;
        }
    }
}

extern "C" void kernel_launch(void* const* d_in, const int* in_sizes, int n_in,
                              void* d_out, int out_size, void* d_ws, size_t ws_size,
                              hipStream_t stream) {
    u16* ws = (u16*)d_ws;
    prep_kernel<<<dim3(18, 9), 256, 0, stream>>>(
        (const float*)d_in[3],  (const float*)d_in[7],  (const float*)d_in[11], (const float*)d_in[15],
        (const float*)d_in[5],  (const float*)d_in[9],  (const float*)d_in[13], (const float*)d_in[17],
        (const float*)d_in[19], ws);

    BiasP bp;
    bp.ba[0] = (const float*)d_in[4];  bp.ba[1] = (const float*)d_in[8];
    bp.ba[2] = (const float*)d_in[12]; bp.ba[3] = (const float*)d_in[16];
    bp.bb[0] = (const float*)d_in[6];  bp.bb[1] = (const float*)d_in[10];
    bp.bb[2] = (const float*)d_in[14]; bp.bb[3] = (const float*)d_in[18];

    fused_kernel<<<NE / 64, 256, 0, stream>>>(
        (const float*)d_in[0], (const int*)d_in[1], (const float*)d_in[2], ws,
        bp, (const float*)d_in[20], (float*)d_out);
}

// Round 7
// 421.478 us; speedup vs baseline: 1.2847x; 1.2847x over previous
//
#include <hip/hip_runtime.h>
#include <hip/hip_bf16.h>

typedef unsigned short u16;
typedef __attribute__((ext_vector_type(8))) short short8;
typedef __attribute__((ext_vector_type(4))) float f32x4;

#define NE 131072

// ws layout in u16 elements (bf16 transposed weights, [n][k] row-major)
#define OFF_WA 0        // 4 x [256][256]
#define OFF_WB 262144   // 4 x [128][256]
#define OFF_WF 393216   // 4 x [128][128]
#define OFF_WE 458752   // [128][32]
#define OFF_WS 462848   // [128]

// async global->LDS, 16B per lane, lane i lands at lds_base + 16*i
#define ASYNC16(gp, lp) __builtin_amdgcn_global_load_lds( \
    (const __attribute__((address_space(1))) unsigned int*)(gp), \
    (__attribute__((address_space(3))) unsigned int*)(lp), 16, 0, 0)
// wait lgkmcnt(0) only: ds_read data in VGPRs before we re-DMA that LDS slot.
#define LGKM0() __builtin_amdgcn_s_waitcnt(0xC07F)
// counted waits for the 3-deep chunk pipeline (2 loads per chunk).
#define WAIT4() asm volatile("s_waitcnt vmcnt(4)" ::: "memory")
#define WAIT2() asm volatile("s_waitcnt vmcnt(2)" ::: "memory")
#define WAIT0() asm volatile("s_waitcnt vmcnt(0)" ::: "memory")
// non-draining barrier: cross-wave data moves only through LDS (ds ops), so
// lgkmcnt(0) + s_barrier is sufficient; the weight DMA (vmcnt) is wave-private
// and intentionally stays in flight across the barrier (T4: never drain).
#define BAR() asm volatile("s_waitcnt lgkmcnt(0)\n\ts_barrier" ::: "memory")

__device__ __forceinline__ float b2f(u16 v) {
    unsigned int u = ((unsigned int)v) << 16;
    float f;
    __builtin_memcpy(&f, &u, 4);
    return f;
}
__device__ __forceinline__ u16 f2b(float f) {
    __hip_bfloat16 h = __float2bfloat16(f);
    u16 u;
    __builtin_memcpy(&u, &h, 2);
    return u;
}
__device__ __forceinline__ short8 pack8(f32x4 a, f32x4 b) {
    short8 p;
    p[0] = (short)f2b(a.x); p[1] = (short)f2b(a.y);
    p[2] = (short)f2b(a.z); p[3] = (short)f2b(a.w);
    p[4] = (short)f2b(b.x); p[5] = (short)f2b(b.y);
    p[6] = (short)f2b(b.z); p[7] = (short)f2b(b.w);
    return p;
}

#define MFMA16(a, b, c) __builtin_amdgcn_mfma_f32_16x16x32_bf16(a, b, c, 0, 0, 0)

struct BiasP {
    const float* ba[4];
    const float* bb[4];
};

// ---- uniform 2-KB weight chunks, wave-private 3-slot rotation, 8 waves ----
// Per m-group 14 chunks: A = 8 x [32 rows][32k] (wave's 32 A-cols),
// B = 4 x [16 rows][64k] (wave's 16 B-cols), C = 2 x [16 rows][64k].
// 56 chunks/block. Chunk gc -> slot (gc % 3) of the wave's 6-KB region.
// k-slot XOR-swizzled identically on DMA source and LDS read (round-5 proven).
__device__ __forceinline__ void issue_chunk(const u16* __restrict__ ws, u16* Wb,
                                            int wave, int lane, int gc) {
    if (gc >= 56) return;
    const int m = gc / 14;
    const int c = gc - m * 14;
    u16* lp = Wb + wave * 3072 + (gc % 3) * 1024;
    if (c < 8) {             // A: Wa_m [256][256], rows = wave*32..+31, k = c*32
        int r = lane >> 2;                          // local row 0..15
        int slot = (lane & 3) ^ ((lane >> 3) & 3);  // swizzle key (r>>1)&3
        const u16* gp = ws + OFF_WA + m * 65536
            + (size_t)(wave * 32 + r) * 256 + c * 32 + slot * 8;
        ASYNC16(gp, lp);
        ASYNC16(gp + 16 * 256, lp + 512);           // rows 16..31
    } else if (c < 12) {     // B: Wb_m [128][256], rows = wave*16..+15, k = kc*64
        int kc = c - 8;
        int nl = lane >> 3, sg = (lane & 7) ^ (nl & 7);
        const u16* gp = ws + OFF_WB + m * 32768
            + (size_t)(wave * 16 + nl) * 256 + kc * 64 + sg * 8;
        ASYNC16(gp, lp);
        ASYNC16(gp + 8 * 256, lp + 512);            // rows 8..15
    } else {                 // C: Wf_m [128][128], rows = wave*16..+15, k = cc*64
        int cc = c - 12;
        int nl = lane >> 3, sg = (lane & 7) ^ (nl & 7);
        const u16* gp = ws + OFF_WF + m * 16384
            + (size_t)(wave * 16 + nl) * 128 + cc * 64 + sg * 8;
        ASYNC16(gp, lp);
        ASYNC16(gp + 8 * 128, lp + 512);            // rows 8..15
    }
}

// LDS-tiled transpose prep: coalesced reads AND writes.
__global__ __launch_bounds__(256)
void prep_kernel(const float* __restrict__ W1a, const float* __restrict__ W2a,
                 const float* __restrict__ W3a, const float* __restrict__ W4a,
                 const float* __restrict__ W1b, const float* __restrict__ W2b,
                 const float* __restrict__ W3b, const float* __restrict__ W4b,
                 const float* __restrict__ Wf,  u16* __restrict__ ws) {
    __shared__ __align__(16) u16 T[64 * 80];

    const int y = blockIdx.y;
    const int t = threadIdx.x;
    const float* in;
    int K, N;
    if (y < 4)      { in = (y == 0) ? W1a : (y == 1) ? W2a : (y == 2) ? W3a : W4a; K = 256; N = 256; }
    else if (y < 8) { in = (y == 4) ? W1b : (y == 5) ? W2b : (y == 6) ? W3b : W4b; K = 256; N = 128; }
    else            { in = Wf; K = 545; N = 128; }

    const int ntilesN = N / 64;
    const int ktiles = (K + 63) / 64;
    const int kt = blockIdx.x / ntilesN;
    const int nt = blockIdx.x - kt * ntilesN;
    if (kt >= ktiles) return;
    const int kbase = kt * 64, nbase = nt * 64;

    {
        int tn = (t & 15) * 4;
        int tk = t >> 4;
        #pragma unroll
        for (int r = 0; r < 4; r++) {
            int k = kbase + tk + 16 * r;
            if (k < K) {
                float4 v = *(const float4*)(in + (size_t)k * N + nbase + tn);
                T[(tn + 0) * 80 + tk + 16 * r] = f2b(v.x);
                T[(tn + 1) * 80 + tk + 16 * r] = f2b(v.y);
                T[(tn + 2) * 80 + tk + 16 * r] = f2b(v.z);
                T[(tn + 3) * 80 + tk + 16 * r] = f2b(v.w);
            }
        }
    }
    __syncthreads();
    {
        int n = t >> 2;
        int kc = (t & 3) * 16;
        int n_out = nbase + n;
        const u16* src = &T[n * 80 + kc];
        if (y < 4) {
            u16* dst = ws + OFF_WA + y * 65536 + (size_t)n_out * 256 + kbase + kc;
            *(short8*)dst = *(const short8*)src;
            *(short8*)(dst + 8) = *(const short8*)(src + 8);
        } else if (y < 8) {
            u16* dst = ws + OFF_WB + (y - 4) * 32768 + (size_t)n_out * 256 + kbase + kc;
            *(short8*)dst = *(const short8*)src;
            *(short8*)(dst + 8) = *(const short8*)(src + 8);
        } else if (kbase < 512) {
            u16* dst = ws + OFF_WF + (kbase >> 7) * 16384 + (size_t)n_out * 128 + (kbase & 127) + kc;
            *(short8*)dst = *(const short8*)src;
            *(short8*)(dst + 8) = *(const short8*)(src + 8);
        } else {
            #pragma unroll
            for (int j = 0; j < 16; j++) {
                int k = kbase + kc + j;
                if (k < 545) {
                    u16 v = src[j];
                    if (k == 512)      ws[OFF_WS + n_out] = v;
                    else               ws[OFF_WE + n_out * 32 + (k - 513)] = v;
                }
            }
        }
    }
}

// 64 edges/block, 8 waves (512 thr), ~147 KB LDS -> 1 block/CU = 2 waves/SIMD.
// Depth-3 counted-vmcnt weight pipeline + non-draining barriers (round-5
// structure), but 2x MFMA per chunk and half the per-edge weight traffic.
// G overlays Hs cols 0..127 (8 waves x 16 C-cols). Barrier order per m:
//   A reads Xs/Xd, writes Hs | BAR_A | B reads Hs | BAR_B2 |
//   G-write (Hs cols<128)    | BAR_B | C reads G  | BAR_C (m<3) |
// Epilogue os overlays Xs (last Xs read is A(3), fenced by BAR_A(3)).
__global__ __launch_bounds__(512, 1)
void fused_kernel(const float* __restrict__ x, const int* __restrict__ ei,
                  const float* __restrict__ ea, const u16* __restrict__ ws,
                  BiasP bp, const float* __restrict__ bfp, float* __restrict__ out) {
    __shared__ __align__(16) u16 Xs[64][264];
    __shared__ __align__(16) u16 Xd[64][264];
    __shared__ __align__(16) u16 Hs[64][264];   // cols 0..127 double as G
    __shared__ __align__(16) u16 Wb[24576];     // 48 KB, 6-KB region per wave (3 slots)
    __shared__ float scos[64];

    const int t = threadIdx.x;
    const int wave = t >> 6;
    const int lane = t & 63;
    const int l15 = lane & 15;
    const int g = lane >> 4;
    const int e0 = blockIdx.x * 64;
    const f32x4 zero4 = {0.f, 0.f, 0.f, 0.f};
    const int colA = wave * 32;      // stage-A column slice (32 cols)
    const int colC = wave * 16;      // stage-B/C column slice (16 cols)

    // Hedge: detect int64 edge_index (sampled high words all zero) vs int32.
    bool idx64 = true;
    #pragma unroll
    for (int i = 1; i < 16; i += 2) { idx64 = idx64 && (ei[i] == 0); }

    // ---- bias hoist (issued before chunk priming -> older vmcnt entries) ----
    float biasA[4][2], biasB[4];
    #pragma unroll
    for (int m = 0; m < 4; m++) {
        #pragma unroll
        for (int nt = 0; nt < 2; nt++) biasA[m][nt] = bp.ba[m][colA + nt * 16 + l15];
        biasB[m] = bp.bb[m][colC + l15];
    }

    // prime the 3-deep pipeline; chunks land during the gather
    issue_chunk(ws, Wb, wave, lane, 0);
    issue_chunk(ws, Wb, wave, lane, 1);
    issue_chunk(ws, Wb, wave, lane, 2);

    // ---- gather (f32 -> bf16 tiles) + cosine similarity in one pass ----
    // 8 lanes per edge, 32 floats per lane.
    {
        int edge = t >> 3;
        int c = t & 7;
        int pos = e0 + edge;
        int is = idx64 ? ei[2 * pos] : ei[pos];
        int id = idx64 ? ei[2 * (NE + pos)] : ei[NE + pos];
        const float* rs = x + (size_t)is * 256 + c * 32;
        const float* rd = x + (size_t)id * 256 + c * 32;
        float dot = 0.f, ss = 0.f, dd = 0.f;
        #pragma unroll
        for (int i = 0; i < 4; i++) {
            f32x4 s0 = *(const f32x4*)(rs + i * 8);
            f32x4 s1 = *(const f32x4*)(rs + i * 8 + 4);
            f32x4 d0 = *(const f32x4*)(rd + i * 8);
            f32x4 d1 = *(const f32x4*)(rd + i * 8 + 4);
            dot += s0.x * d0.x + s0.y * d0.y + s0.z * d0.z + s0.w * d0.w
                 + s1.x * d1.x + s1.y * d1.y + s1.z * d1.z + s1.w * d1.w;
            ss  += s0.x * s0.x + s0.y * s0.y + s0.z * s0.z + s0.w * s0.w
                 + s1.x * s1.x + s1.y * s1.y + s1.z * s1.z + s1.w * s1.w;
            dd  += d0.x * d0.x + d0.y * d0.y + d0.z * d0.z + d0.w * d0.w
                 + d1.x * d1.x + d1.y * d1.y + d1.z * d1.z + d1.w * d1.w;
            *(short8*)(&Xs[edge][c * 32 + i * 8]) = pack8(s0, s1);
            *(short8*)(&Xd[edge][c * 32 + i * 8]) = pack8(d0, d1);
        }
        dot += __shfl_xor(dot, 1); ss += __shfl_xor(ss, 1); dd += __shfl_xor(dd, 1);
        dot += __shfl_xor(dot, 2); ss += __shfl_xor(ss, 2); dd += __shfl_xor(dd, 2);
        dot += __shfl_xor(dot, 4); ss += __shfl_xor(ss, 4); dd += __shfl_xor(dd, 4);
        if (c == 0) {
            float ns = fmaxf(sqrtf(ss), 1e-8f);
            float nd = fmaxf(sqrtf(dd), 1e-8f);
            scos[edge] = dot / (ns * nd);
        }
    }
    BAR();             // gather barrier: Xs/Xd/scos visible; DMA stays in flight

    // ---- LDS read base pointers (per mt row-group) ----
    const u16* xsb[4]; const u16* xdb[4]; const u16* hgb[4];
    #pragma unroll
    for (int mt = 0; mt < 4; mt++) {
        xsb[mt] = &Xs[mt * 16 + l15][g * 8];
        xdb[mt] = &Xd[mt * 16 + l15][g * 8];
        hgb[mt] = &Hs[mt * 16 + l15][g * 8];
    }
    // A-chunk read base: row = l15 (+16 via +512), slot g swizzled by (l15>>1)&3
    const u16* wbaseA = Wb + wave * 3072 + l15 * 32 + ((g ^ ((l15 >> 1) & 3)) * 8);
    // B/C-chunk read base: row = l15, 64 u16/row; slot (kk2*4+g)^(l15&7) applied per use
    const u16* wbaseB = Wb + wave * 3072 + l15 * 64;

    f32x4 Facc[4];
    #pragma unroll
    for (int a = 0; a < 4; a++) Facc[a] = zero4;

    #pragma unroll
    for (int m = 0; m < 4; m++) {
        // ===== stage A: H = relu(A @ Wa + ba) ===== (8 chunks of 32-k, 32 cols)
        f32x4 accA[4][2];
        #pragma unroll
        for (int a = 0; a < 4; a++) {
            #pragma unroll
            for (int b = 0; b < 2; b++) accA[a][b] = zero4;
        }
        #pragma unroll
        for (int kk = 0; kk < 8; kk++) {
            const int gc = m * 14 + kk;
            // af frags first (stable LDS + VALU repack overlap the DMA wait)
            short8 af[4];
            #pragma unroll
            for (int mt = 0; mt < 4; mt++) {
                if (m == 0)      af[mt] = *(const short8*)(xsb[mt] + kk * 32);
                else if (m == 1) af[mt] = *(const short8*)(xdb[mt] + kk * 32);
                else {
                    short8 s = *(const short8*)(xsb[mt] + kk * 32);
                    short8 d = *(const short8*)(xdb[mt] + kk * 32);
                    short8 rr;
                    #pragma unroll
                    for (int j = 0; j < 8; j++) {
                        float fs = b2f((u16)s[j]);
                        float fd = b2f((u16)d[j]);
                        rr[j] = (short)f2b((m == 2) ? (fs - fd) : (fs * fd));
                    }
                    af[mt] = rr;
                }
            }
            WAIT4();
            const u16* wq = wbaseA + (gc % 3) * 1024;
            short8 wf0 = *(const short8*)(wq);          // cols colA+0..15
            short8 wf1 = *(const short8*)(wq + 512);    // cols colA+16..31
            LGKM0();
            issue_chunk(ws, Wb, wave, lane, gc + 3);
            #pragma unroll
            for (int mt = 0; mt < 4; mt++) {
                accA[mt][0] = MFMA16(af[mt], wf0, accA[mt][0]);
                accA[mt][1] = MFMA16(af[mt], wf1, accA[mt][1]);
            }
        }
        #pragma unroll
        for (int nt = 0; nt < 2; nt++) {
            int col = colA + nt * 16 + l15;
            #pragma unroll
            for (int mt = 0; mt < 4; mt++) {
                #pragma unroll
                for (int rg = 0; rg < 4; rg++) {
                    int row = mt * 16 + g * 4 + rg;
                    Hs[row][col] = f2b(fmaxf(accA[mt][nt][rg] + biasA[m][nt], 0.f));
                }
            }
        }
        BAR();                                   // BAR_A: Hs ready (DMA in flight)

        // ===== stage B: G = relu(H @ Wb + bb) ===== (4 chunks of 64-k, 16 cols)
        f32x4 accB[4];
        #pragma unroll
        for (int a = 0; a < 4; a++) accB[a] = zero4;
        #pragma unroll
        for (int kc = 0; kc < 4; kc++) {
            const int gc = m * 14 + 8 + kc;
            short8 hf[4][2];
            #pragma unroll
            for (int mt = 0; mt < 4; mt++) {
                hf[mt][0] = *(const short8*)(hgb[mt] + kc * 64);
                hf[mt][1] = *(const short8*)(hgb[mt] + kc * 64 + 32);
            }
            WAIT4();
            const u16* wq = wbaseB + (gc % 3) * 1024;
            short8 wf0 = *(const short8*)(wq + (((0 * 4 + g) ^ (l15 & 7)) * 8));
            short8 wf1 = *(const short8*)(wq + (((1 * 4 + g) ^ (l15 & 7)) * 8));
            LGKM0();
            issue_chunk(ws, Wb, wave, lane, gc + 3);
            #pragma unroll
            for (int mt = 0; mt < 4; mt++) {
                accB[mt] = MFMA16(hf[mt][0], wf0, accB[mt]);
                accB[mt] = MFMA16(hf[mt][1], wf1, accB[mt]);
            }
        }
        BAR();                                   // BAR_B2: all H reads done
        {
            int col = colC + l15;                // cols 0..127: G overlays Hs
            #pragma unroll
            for (int mt = 0; mt < 4; mt++) {
                #pragma unroll
                for (int rg = 0; rg < 4; rg++) {
                    int row = mt * 16 + g * 4 + rg;
                    Hs[row][col] = f2b(fmaxf(accB[mt][rg] + biasB[m], 0.f));
                }
            }
        }
        BAR();                                   // BAR_B: G ready

        // ===== stage C: Facc += G @ WfT_m ===== (2 chunks of 64-k, 16 cols)
        #pragma unroll
        for (int cc = 0; cc < 2; cc++) {
            const int gc = m * 14 + 12 + cc;
            short8 gf[4][2];
            #pragma unroll
            for (int mt = 0; mt < 4; mt++) {
                gf[mt][0] = *(const short8*)(hgb[mt] + cc * 64);
                gf[mt][1] = *(const short8*)(hgb[mt] + cc * 64 + 32);
            }
            // tail ramp-down: gc=54 -> only {54,55} outstanding; gc=55 -> {55}
            if (m == 3 && cc == 0)      { WAIT2(); }
            else if (m == 3 && cc == 1) { WAIT0(); }
            else                        { WAIT4(); }
            const u16* wq = wbaseB + (gc % 3) * 1024;
            short8 wf0 = *(const short8*)(wq + (((0 * 4 + g) ^ (l15 & 7)) * 8));
            short8 wf1 = *(const short8*)(wq + (((1 * 4 + g) ^ (l15 & 7)) * 8));
            LGKM0();
            issue_chunk(ws, Wb, wave, lane, gc + 3);
            #pragma unroll
            for (int mt = 0; mt < 4; mt++) {
                Facc[mt] = MFMA16(gf[mt][0], wf0, Facc[mt]);
                Facc[mt] = MFMA16(gf[mt][1], wf1, Facc[mt]);
            }
        }
        if (m < 3) BAR();                        // BAR_C: G reads done before Hs(m+1) writes
    }

    // ===== edge_attr contribution (loaded after m-loop: dead across it) =====
    short8 eaA[4], eaB;
    float epi_b, epi_w;
    #pragma unroll
    for (int mt = 0; mt < 4; mt++) {
        const float* er = ea + (size_t)(e0 + mt * 16 + l15) * 32 + g * 8;
        f32x4 a = *(const f32x4*)(er);
        f32x4 b = *(const f32x4*)(er + 4);
        eaA[mt] = pack8(a, b);
    }
    {
        int col = colC + l15;
        eaB = *(const short8*)(ws + OFF_WE + col * 32 + g * 8);
        epi_b = bfp[col];
        epi_w = b2f(ws[OFF_WS + col]);
    }
    #pragma unroll
    for (int mt = 0; mt < 4; mt++) {
        Facc[mt] = MFMA16(eaA[mt], eaB, Facc[mt]);
    }

    // ===== epilogue: + s*Wf[512] + bf, tanh, stage f32 in LDS, coalesced store =====
    float* os = (float*)&Xs[0][0];   // reuse Xs: 64 x 132 f32 = 33792 B (exact fit)
    {
        int col = colC + l15;
        #pragma unroll
        for (int mt = 0; mt < 4; mt++) {
            #pragma unroll
            for (int rg = 0; rg < 4; rg++) {
                int row = mt * 16 + g * 4 + rg;
                float v = Facc[mt][rg] + scos[row] * epi_w + epi_b;
                v = fminf(fmaxf(v, -15.f), 15.f);
                float e2 = __expf(2.f * v);
                os[row * 132 + col] = (e2 - 1.f) / (e2 + 1.f);
            }
        }
    }
    BAR();
    {
        int row = t >> 3, c = t & 7;
        float* op = out + (size_t)(e0 + row) * 128 + c * 16;
        const float* sp = os + row * 132 + c * 16;
        #pragma unroll
        for (int i = 0; i < 4; i++) {
            f32x4 v = *(const f32x4*)(sp + i * 4);
            *(f32x4*)(op + i * 4) = v;
        }
    }
}

extern "C" void kernel_launch(void* const* d_in, const int* in_sizes, int n_in,
                              void* d_out, int out_size, void* d_ws, size_t ws_size,
                              hipStream_t stream) {
    u16* ws = (u16*)d_ws;
    prep_kernel<<<dim3(18, 9), 256, 0, stream>>>(
        (const float*)d_in[3],  (const float*)d_in[7],  (const float*)d_in[11], (const float*)d_in[15],
        (const float*)d_in[5],  (const float*)d_in[9],  (const float*)d_in[13], (const float*)d_in[17],
        (const float*)d_in[19], ws);

    BiasP bp;
    bp.ba[0] = (const float*)d_in[4];  bp.ba[1] = (const float*)d_in[8];
    bp.ba[2] = (const float*)d_in[12]; bp.ba[3] = (const float*)d_in[16];
    bp.bb[0] = (const float*)d_in[6];  bp.bb[1] = (const float*)d_in[10];
    bp.bb[2] = (const float*)d_in[14]; bp.bb[3] = (const float*)d_in[18];

    fused_kernel<<<NE / 64, 512, 0, stream>>>(
        (const float*)d_in[0], (const int*)d_in[1], (const float*)d_in[2], ws,
        bp, (const float*)d_in[20], (float*)d_out);
}

// Round 8
// 391.109 us; speedup vs baseline: 1.3845x; 1.0776x over previous
//
#include <hip/hip_runtime.h>
#include <hip/hip_bf16.h>

typedef unsigned short u16;
typedef __attribute__((ext_vector_type(8))) short short8;
typedef __attribute__((ext_vector_type(4))) float f32x4;

#define NE 131072

// ws layout in u16 elements (bf16 transposed weights, [n][k] row-major)
#define OFF_WA 0        // 4 x [256][256]
#define OFF_WB 262144   // 4 x [128][256]
#define OFF_WF 393216   // 4 x [128][128]
#define OFF_WE 458752   // [128][32]
#define OFF_WS 462848   // [128]

// async global->LDS, 16B per lane, lane i lands at lds_base + 16*i
#define ASYNC16(gp, lp) __builtin_amdgcn_global_load_lds( \
    (const __attribute__((address_space(1))) unsigned int*)(gp), \
    (__attribute__((address_space(3))) unsigned int*)(lp), 16, 0, 0)
// wait lgkmcnt(0) only: ds_read data in VGPRs before we re-DMA that LDS slot.
#define LGKM0() __builtin_amdgcn_s_waitcnt(0xC07F)
// counted waits for the 3-deep chunk pipeline (2 loads per chunk).
#define WAIT4() asm volatile("s_waitcnt vmcnt(4)" ::: "memory")
#define WAIT2() asm volatile("s_waitcnt vmcnt(2)" ::: "memory")
#define WAIT0() asm volatile("s_waitcnt vmcnt(0)" ::: "memory")
// non-draining barrier: cross-wave data moves only through LDS (ds ops), so
// lgkmcnt(0) + s_barrier is sufficient; the weight DMA (vmcnt) is wave-private
// and intentionally stays in flight across the barrier (T4: never drain).
#define BAR() asm volatile("s_waitcnt lgkmcnt(0)\n\ts_barrier" ::: "memory")

__device__ __forceinline__ float b2f(u16 v) {
    unsigned int u = ((unsigned int)v) << 16;
    float f;
    __builtin_memcpy(&f, &u, 4);
    return f;
}
__device__ __forceinline__ u16 f2b(float f) {
    __hip_bfloat16 h = __float2bfloat16(f);
    u16 u;
    __builtin_memcpy(&u, &h, 2);
    return u;
}
__device__ __forceinline__ short8 pack8(f32x4 a, f32x4 b) {
    short8 p;
    p[0] = (short)f2b(a.x); p[1] = (short)f2b(a.y);
    p[2] = (short)f2b(a.z); p[3] = (short)f2b(a.w);
    p[4] = (short)f2b(b.x); p[5] = (short)f2b(b.y);
    p[6] = (short)f2b(b.z); p[7] = (short)f2b(b.w);
    return p;
}

#define MFMA16(a, b, c) __builtin_amdgcn_mfma_f32_16x16x32_bf16(a, b, c, 0, 0, 0)

struct BiasP {
    const float* ba[4];
    const float* bb[4];
};

// ---- uniform 2-KB weight chunks, wave-private 3-slot rotation, 8 waves ----
// Per m-group 14 chunks: A = 8 x [32 rows][32k] (wave's 32 A-cols),
// B = 4 x [16 rows][64k] (wave's 16 B-cols), C = 2 x [16 rows][64k].
// 56 chunks/block. Chunk gc -> slot (gc % 3) of the wave's 6-KB region.
// k-slot XOR-swizzled identically on DMA source and LDS read (round-5 proven).
__device__ __forceinline__ void issue_chunk(const u16* __restrict__ ws, u16* Wb,
                                            int wave, int lane, int gc) {
    if (gc >= 56) return;
    const int m = gc / 14;
    const int c = gc - m * 14;
    u16* lp = Wb + wave * 3072 + (gc % 3) * 1024;
    if (c < 8) {             // A: Wa_m [256][256], rows = wave*32..+31, k = c*32
        int r = lane >> 2;                          // local row 0..15
        int slot = (lane & 3) ^ ((lane >> 3) & 3);  // swizzle key (r>>1)&3
        const u16* gp = ws + OFF_WA + m * 65536
            + (size_t)(wave * 32 + r) * 256 + c * 32 + slot * 8;
        ASYNC16(gp, lp);
        ASYNC16(gp + 16 * 256, lp + 512);           // rows 16..31
    } else if (c < 12) {     // B: Wb_m [128][256], rows = wave*16..+15, k = kc*64
        int kc = c - 8;
        int nl = lane >> 3, sg = (lane & 7) ^ (nl & 7);
        const u16* gp = ws + OFF_WB + m * 32768
            + (size_t)(wave * 16 + nl) * 256 + kc * 64 + sg * 8;
        ASYNC16(gp, lp);
        ASYNC16(gp + 8 * 256, lp + 512);            // rows 8..15
    } else {                 // C: Wf_m [128][128], rows = wave*16..+15, k = cc*64
        int cc = c - 12;
        int nl = lane >> 3, sg = (lane & 7) ^ (nl & 7);
        const u16* gp = ws + OFF_WF + m * 16384
            + (size_t)(wave * 16 + nl) * 128 + cc * 64 + sg * 8;
        ASYNC16(gp, lp);
        ASYNC16(gp + 8 * 128, lp + 512);            // rows 8..15
    }
}

// LDS-tiled transpose prep: coalesced reads AND writes.
__global__ __launch_bounds__(256)
void prep_kernel(const float* __restrict__ W1a, const float* __restrict__ W2a,
                 const float* __restrict__ W3a, const float* __restrict__ W4a,
                 const float* __restrict__ W1b, const float* __restrict__ W2b,
                 const float* __restrict__ W3b, const float* __restrict__ W4b,
                 const float* __restrict__ Wf,  u16* __restrict__ ws) {
    __shared__ __align__(16) u16 T[64 * 80];

    const int y = blockIdx.y;
    const int t = threadIdx.x;
    const float* in;
    int K, N;
    if (y < 4)      { in = (y == 0) ? W1a : (y == 1) ? W2a : (y == 2) ? W3a : W4a; K = 256; N = 256; }
    else if (y < 8) { in = (y == 4) ? W1b : (y == 5) ? W2b : (y == 6) ? W3b : W4b; K = 256; N = 128; }
    else            { in = Wf; K = 545; N = 128; }

    const int ntilesN = N / 64;
    const int ktiles = (K + 63) / 64;
    const int kt = blockIdx.x / ntilesN;
    const int nt = blockIdx.x - kt * ntilesN;
    if (kt >= ktiles) return;
    const int kbase = kt * 64, nbase = nt * 64;

    {
        int tn = (t & 15) * 4;
        int tk = t >> 4;
        #pragma unroll
        for (int r = 0; r < 4; r++) {
            int k = kbase + tk + 16 * r;
            if (k < K) {
                float4 v = *(const float4*)(in + (size_t)k * N + nbase + tn);
                T[(tn + 0) * 80 + tk + 16 * r] = f2b(v.x);
                T[(tn + 1) * 80 + tk + 16 * r] = f2b(v.y);
                T[(tn + 2) * 80 + tk + 16 * r] = f2b(v.z);
                T[(tn + 3) * 80 + tk + 16 * r] = f2b(v.w);
            }
        }
    }
    __syncthreads();
    {
        int n = t >> 2;
        int kc = (t & 3) * 16;
        int n_out = nbase + n;
        const u16* src = &T[n * 80 + kc];
        if (y < 4) {
            u16* dst = ws + OFF_WA + y * 65536 + (size_t)n_out * 256 + kbase + kc;
            *(short8*)dst = *(const short8*)src;
            *(short8*)(dst + 8) = *(const short8*)(src + 8);
        } else if (y < 8) {
            u16* dst = ws + OFF_WB + (y - 4) * 32768 + (size_t)n_out * 256 + kbase + kc;
            *(short8*)dst = *(const short8*)src;
            *(short8*)(dst + 8) = *(const short8*)(src + 8);
        } else if (kbase < 512) {
            u16* dst = ws + OFF_WF + (kbase >> 7) * 16384 + (size_t)n_out * 128 + (kbase & 127) + kc;
            *(short8*)dst = *(const short8*)src;
            *(short8*)(dst + 8) = *(const short8*)(src + 8);
        } else {
            #pragma unroll
            for (int j = 0; j < 16; j++) {
                int k = kbase + kc + j;
                if (k < 545) {
                    u16 v = src[j];
                    if (k == 512)      ws[OFF_WS + n_out] = v;
                    else               ws[OFF_WE + n_out * 32 + (k - 513)] = v;
                }
            }
        }
    }
}

// 64 edges/block, 8 waves (512 thr), ~151 KB LDS -> 1 block/CU = 2 waves/SIMD.
// Round-7 structure + ONE-TIME in-place transform: after BAR_A(m=1) (all raw
// Xs reads done at m=0, all raw Xd reads done at m=1), all 512 threads rewrite
//   Xs <- bf16(s - d), Xd <- bf16(s * d)
// so stages m=2/m=3 read A-frags with a single ds_read like m=0/m=1 (kills the
// 8x-redundant per-wave per-kk repack that made round 7 VALU-bound).
// Transform-vs-read fencing: writes happen between BAR_A(m=1) and BAR_B2(m=1);
// first transformed read is m=2's A-loop, after BAR_C(m=1). No extra barrier.
__global__ __launch_bounds__(512, 1)
void fused_kernel(const float* __restrict__ x, const int* __restrict__ ei,
                  const float* __restrict__ ea, const u16* __restrict__ ws,
                  BiasP bp, const float* __restrict__ bfp, float* __restrict__ out) {
    __shared__ __align__(16) u16 Xs[64][264];
    __shared__ __align__(16) u16 Xd[64][264];
    __shared__ __align__(16) u16 Hs[64][264];   // cols 0..127 double as G
    __shared__ __align__(16) u16 Wb[24576];     // 48 KB, 6-KB region per wave (3 slots)
    __shared__ float scos[64];

    const int t = threadIdx.x;
    const int wave = t >> 6;
    const int lane = t & 63;
    const int l15 = lane & 15;
    const int g = lane >> 4;
    const int e0 = blockIdx.x * 64;
    const f32x4 zero4 = {0.f, 0.f, 0.f, 0.f};
    const int colA = wave * 32;      // stage-A column slice (32 cols)
    const int colC = wave * 16;      // stage-B/C column slice (16 cols)

    // Hedge: detect int64 edge_index (sampled high words all zero) vs int32.
    bool idx64 = true;
    #pragma unroll
    for (int i = 1; i < 16; i += 2) { idx64 = idx64 && (ei[i] == 0); }

    // ---- bias hoist (issued before chunk priming -> older vmcnt entries) ----
    float biasA[4][2], biasB[4];
    #pragma unroll
    for (int m = 0; m < 4; m++) {
        #pragma unroll
        for (int nt = 0; nt < 2; nt++) biasA[m][nt] = bp.ba[m][colA + nt * 16 + l15];
        biasB[m] = bp.bb[m][colC + l15];
    }

    // prime the 3-deep pipeline; chunks land during the gather
    issue_chunk(ws, Wb, wave, lane, 0);
    issue_chunk(ws, Wb, wave, lane, 1);
    issue_chunk(ws, Wb, wave, lane, 2);

    // ---- gather (f32 -> bf16 tiles) + cosine similarity in one pass ----
    // 8 lanes per edge, 32 floats per lane.
    {
        int edge = t >> 3;
        int c = t & 7;
        int pos = e0 + edge;
        int is = idx64 ? ei[2 * pos] : ei[pos];
        int id = idx64 ? ei[2 * (NE + pos)] : ei[NE + pos];
        const float* rs = x + (size_t)is * 256 + c * 32;
        const float* rd = x + (size_t)id * 256 + c * 32;
        float dot = 0.f, ss = 0.f, dd = 0.f;
        #pragma unroll
        for (int i = 0; i < 4; i++) {
            f32x4 s0 = *(const f32x4*)(rs + i * 8);
            f32x4 s1 = *(const f32x4*)(rs + i * 8 + 4);
            f32x4 d0 = *(const f32x4*)(rd + i * 8);
            f32x4 d1 = *(const f32x4*)(rd + i * 8 + 4);
            dot += s0.x * d0.x + s0.y * d0.y + s0.z * d0.z + s0.w * d0.w
                 + s1.x * d1.x + s1.y * d1.y + s1.z * d1.z + s1.w * d1.w;
            ss  += s0.x * s0.x + s0.y * s0.y + s0.z * s0.z + s0.w * s0.w
                 + s1.x * s1.x + s1.y * s1.y + s1.z * s1.z + s1.w * s1.w;
            dd  += d0.x * d0.x + d0.y * d0.y + d0.z * d0.z + d0.w * d0.w
                 + d1.x * d1.x + d1.y * d1.y + d1.z * d1.z + d1.w * d1.w;
            *(short8*)(&Xs[edge][c * 32 + i * 8]) = pack8(s0, s1);
            *(short8*)(&Xd[edge][c * 32 + i * 8]) = pack8(d0, d1);
        }
        dot += __shfl_xor(dot, 1); ss += __shfl_xor(ss, 1); dd += __shfl_xor(dd, 1);
        dot += __shfl_xor(dot, 2); ss += __shfl_xor(ss, 2); dd += __shfl_xor(dd, 2);
        dot += __shfl_xor(dot, 4); ss += __shfl_xor(ss, 4); dd += __shfl_xor(dd, 4);
        if (c == 0) {
            float ns = fmaxf(sqrtf(ss), 1e-8f);
            float nd = fmaxf(sqrtf(dd), 1e-8f);
            scos[edge] = dot / (ns * nd);
        }
    }
    BAR();             // gather barrier: Xs/Xd/scos visible; DMA stays in flight

    // ---- LDS read base pointers (per mt row-group) ----
    const u16* xsb[4]; const u16* xdb[4]; const u16* hgb[4];
    #pragma unroll
    for (int mt = 0; mt < 4; mt++) {
        xsb[mt] = &Xs[mt * 16 + l15][g * 8];
        xdb[mt] = &Xd[mt * 16 + l15][g * 8];
        hgb[mt] = &Hs[mt * 16 + l15][g * 8];
    }
    // A-chunk read base: row = l15 (+16 via +512), slot g swizzled by (l15>>1)&3
    const u16* wbaseA = Wb + wave * 3072 + l15 * 32 + ((g ^ ((l15 >> 1) & 3)) * 8);
    // B/C-chunk read base: row = l15, 64 u16/row; slot (kk2*4+g)^(l15&7) applied per use
    const u16* wbaseB = Wb + wave * 3072 + l15 * 64;

    f32x4 Facc[4];
    #pragma unroll
    for (int a = 0; a < 4; a++) Facc[a] = zero4;

    #pragma unroll
    for (int m = 0; m < 4; m++) {
        // ===== stage A: H = relu(A @ Wa + ba) ===== (8 chunks of 32-k, 32 cols)
        // m=0: A=Xs(raw); m=1: A=Xd(raw); m=2: A=Xs(=s-d); m=3: A=Xd(=s*d)
        f32x4 accA[4][2];
        #pragma unroll
        for (int a = 0; a < 4; a++) {
            #pragma unroll
            for (int b = 0; b < 2; b++) accA[a][b] = zero4;
        }
        #pragma unroll
        for (int kk = 0; kk < 8; kk++) {
            const int gc = m * 14 + kk;
            short8 af[4];
            #pragma unroll
            for (int mt = 0; mt < 4; mt++) {
                af[mt] = (m == 0 || m == 2) ? *(const short8*)(xsb[mt] + kk * 32)
                                            : *(const short8*)(xdb[mt] + kk * 32);
            }
            WAIT4();
            const u16* wq = wbaseA + (gc % 3) * 1024;
            short8 wf0 = *(const short8*)(wq);          // cols colA+0..15
            short8 wf1 = *(const short8*)(wq + 512);    // cols colA+16..31
            LGKM0();
            issue_chunk(ws, Wb, wave, lane, gc + 3);
            #pragma unroll
            for (int mt = 0; mt < 4; mt++) {
                accA[mt][0] = MFMA16(af[mt], wf0, accA[mt][0]);
                accA[mt][1] = MFMA16(af[mt], wf1, accA[mt][1]);
            }
        }
        #pragma unroll
        for (int nt = 0; nt < 2; nt++) {
            int col = colA + nt * 16 + l15;
            #pragma unroll
            for (int mt = 0; mt < 4; mt++) {
                #pragma unroll
                for (int rg = 0; rg < 4; rg++) {
                    int row = mt * 16 + g * 4 + rg;
                    Hs[row][col] = f2b(fmaxf(accA[mt][nt][rg] + biasA[m][nt], 0.f));
                }
            }
        }
        BAR();                                   // BAR_A: Hs ready (DMA in flight)

        if (m == 1) {
            // ---- one-time in-place transform: Xs <- s-d, Xd <- s*d ----
            // All raw reads done (m=0 A-loop read Xs, m=1 A-loop read Xd; both
            // fenced by BAR_A(m=1)). Each thread owns a disjoint 32-col slice
            // of one row. First transformed read is after BAR_C(m=1).
            int row = t >> 3;
            int c0 = (t & 7) * 32;
            u16* ps = &Xs[row][c0];
            u16* pd = &Xd[row][c0];
            #pragma unroll
            for (int i = 0; i < 4; i++) {
                short8 s = *(short8*)(ps + i * 8);
                short8 d = *(short8*)(pd + i * 8);
                short8 sb, mb;
                #pragma unroll
                for (int j = 0; j < 8; j++) {
                    float fs = b2f((u16)s[j]);
                    float fd = b2f((u16)d[j]);
                    sb[j] = (short)f2b(fs - fd);
                    mb[j] = (short)f2b(fs * fd);
                }
                *(short8*)(ps + i * 8) = sb;
                *(short8*)(pd + i * 8) = mb;
            }
        }

        // ===== stage B: G = relu(H @ Wb + bb) ===== (4 chunks of 64-k, 16 cols)
        f32x4 accB[4];
        #pragma unroll
        for (int a = 0; a < 4; a++) accB[a] = zero4;
        #pragma unroll
        for (int kc = 0; kc < 4; kc++) {
            const int gc = m * 14 + 8 + kc;
            short8 hf[4][2];
            #pragma unroll
            for (int mt = 0; mt < 4; mt++) {
                hf[mt][0] = *(const short8*)(hgb[mt] + kc * 64);
                hf[mt][1] = *(const short8*)(hgb[mt] + kc * 64 + 32);
            }
            WAIT4();
            const u16* wq = wbaseB + (gc % 3) * 1024;
            short8 wf0 = *(const short8*)(wq + (((0 * 4 + g) ^ (l15 & 7)) * 8));
            short8 wf1 = *(const short8*)(wq + (((1 * 4 + g) ^ (l15 & 7)) * 8));
            LGKM0();
            issue_chunk(ws, Wb, wave, lane, gc + 3);
            #pragma unroll
            for (int mt = 0; mt < 4; mt++) {
                accB[mt] = MFMA16(hf[mt][0], wf0, accB[mt]);
                accB[mt] = MFMA16(hf[mt][1], wf1, accB[mt]);
            }
        }
        BAR();                                   // BAR_B2: all H reads done
        {
            int col = colC + l15;                // cols 0..127: G overlays Hs
            #pragma unroll
            for (int mt = 0; mt < 4; mt++) {
                #pragma unroll
                for (int rg = 0; rg < 4; rg++) {
                    int row = mt * 16 + g * 4 + rg;
                    Hs[row][col] = f2b(fmaxf(accB[mt][rg] + biasB[m], 0.f));
                }
            }
        }
        BAR();                                   // BAR_B: G ready

        // ===== stage C: Facc += G @ WfT_m ===== (2 chunks of 64-k, 16 cols)
        #pragma unroll
        for (int cc = 0; cc < 2; cc++) {
            const int gc = m * 14 + 12 + cc;
            short8 gf[4][2];
            #pragma unroll
            for (int mt = 0; mt < 4; mt++) {
                gf[mt][0] = *(const short8*)(hgb[mt] + cc * 64);
                gf[mt][1] = *(const short8*)(hgb[mt] + cc * 64 + 32);
            }
            // tail ramp-down: gc=54 -> only {54,55} outstanding; gc=55 -> {55}
            if (m == 3 && cc == 0)      { WAIT2(); }
            else if (m == 3 && cc == 1) { WAIT0(); }
            else                        { WAIT4(); }
            const u16* wq = wbaseB + (gc % 3) * 1024;
            short8 wf0 = *(const short8*)(wq + (((0 * 4 + g) ^ (l15 & 7)) * 8));
            short8 wf1 = *(const short8*)(wq + (((1 * 4 + g) ^ (l15 & 7)) * 8));
            LGKM0();
            issue_chunk(ws, Wb, wave, lane, gc + 3);
            #pragma unroll
            for (int mt = 0; mt < 4; mt++) {
                Facc[mt] = MFMA16(gf[mt][0], wf0, Facc[mt]);
                Facc[mt] = MFMA16(gf[mt][1], wf1, Facc[mt]);
            }
        }
        if (m < 3) BAR();                        // BAR_C: G reads done before Hs(m+1) writes
    }

    // ===== edge_attr contribution (loaded after m-loop: dead across it) =====
    short8 eaA[4], eaB;
    float epi_b, epi_w;
    #pragma unroll
    for (int mt = 0; mt < 4; mt++) {
        const float* er = ea + (size_t)(e0 + mt * 16 + l15) * 32 + g * 8;
        f32x4 a = *(const f32x4*)(er);
        f32x4 b = *(const f32x4*)(er + 4);
        eaA[mt] = pack8(a, b);
    }
    {
        int col = colC + l15;
        eaB = *(const short8*)(ws + OFF_WE + col * 32 + g * 8);
        epi_b = bfp[col];
        epi_w = b2f(ws[OFF_WS + col]);
    }
    #pragma unroll
    for (int mt = 0; mt < 4; mt++) {
        Facc[mt] = MFMA16(eaA[mt], eaB, Facc[mt]);
    }

    // ===== epilogue: + s*Wf[512] + bf, tanh, stage f32 in LDS, coalesced store =====
    float* os = (float*)&Xs[0][0];   // reuse Xs: 64 x 132 f32 = 33792 B (exact fit)
    {
        int col = colC + l15;
        #pragma unroll
        for (int mt = 0; mt < 4; mt++) {
            #pragma unroll
            for (int rg = 0; rg < 4; rg++) {
                int row = mt * 16 + g * 4 + rg;
                float v = Facc[mt][rg] + scos[row] * epi_w + epi_b;
                v = fminf(fmaxf(v, -15.f), 15.f);
                float e2 = __expf(2.f * v);
                os[row * 132 + col] = (e2 - 1.f) / (e2 + 1.f);
            }
        }
    }
    BAR();
    {
        int row = t >> 3, c = t & 7;
        float* op = out + (size_t)(e0 + row) * 128 + c * 16;
        const float* sp = os + row * 132 + c * 16;
        #pragma unroll
        for (int i = 0; i < 4; i++) {
            f32x4 v = *(const f32x4*)(sp + i * 4);
            *(f32x4*)(op + i * 4) = v;
        }
    }
}

extern "C" void kernel_launch(void* const* d_in, const int* in_sizes, int n_in,
                              void* d_out, int out_size, void* d_ws, size_t ws_size,
                              hipStream_t stream) {
    u16* ws = (u16*)d_ws;
    prep_kernel<<<dim3(18, 9), 256, 0, stream>>>(
        (const float*)d_in[3],  (const float*)d_in[7],  (const float*)d_in[11], (const float*)d_in[15],
        (const float*)d_in[5],  (const float*)d_in[9],  (const float*)d_in[13], (const float*)d_in[17],
        (const float*)d_in[19], ws);

    BiasP bp;
    bp.ba[0] = (const float*)d_in[4];  bp.ba[1] = (const float*)d_in[8];
    bp.ba[2] = (const float*)d_in[12]; bp.ba[3] = (const float*)d_in[16];
    bp.bb[0] = (const float*)d_in[6];  bp.bb[1] = (const float*)d_in[10];
    bp.bb[2] = (const float*)d_in[14]; bp.bb[3] = (const float*)d_in[18];

    fused_kernel<<<NE / 64, 512, 0, stream>>>(
        (const float*)d_in[0], (const int*)d_in[1], (const float*)d_in[2], ws,
        bp, (const float*)d_in[20], (float*)d_out);
}